// Round 10
// baseline (123.351 us; speedup 1.0000x reference)
//
#include <hip/hip_runtime.h>

// StructureTensorEffect: B=4, C=3, H=W=1024, fp32.
// Round 16: cut LDS instruction COUNT via x-vectorized ds_read_b128.
// R15 (border fix) moved st 41.5->37.5 -- first confirmed lever. The
// remaining plateau finally has a model that fits: per-CU DS issue.
// All scalar-tap structures do 5 ds_read_b32 x 12 rows x 3ch = 180 DS
// instrs/thread-tile = 23K/CU; at ~4-5.8cy issue (m134) = 37-53us = the
// plateau, invariant across R7-R14 (R14 reordered but didn't reduce
// count -> null; R12 reduced 20% but added 491K bank conflicts).
// This round: same 64x32 tile, threads re-mapped to 4 cols x 2 rows
// (same 8 px). Per (window row, ch): 3 aligned ds_read_b128 (12 dwords
// serve all taps of 4 cols) = 36-72 DS/thread-tile (3.3x cut).
// Alignment: X = 4*xg, LSTRIDE = 76 (mult of 4 -> 16B rows; 76 mod 32
// banks = 12/row -> rows {0,24,16,8} distinct quads, even distribution).
// Math: separable d/e form (d = hp-hm, e = 0.25(hm+hp)+0.5cc; vertical
// weights {fp4,fm4,0.5,fm4,fp4}/{-fp,-fm,fm,fp}) -- same taps, same
// weights, reassociated only. Stores stay 24 scalar dwords/thread so
// R13's proven vmcnt(9) pipeline bookkeeping is unchanged. Staging,
// persistent 4-band blocks, x-border tiles, y-border rows = R15 verbatim
// (GPR 18->19 groups for the 76-col window).

#define W_ 1024
#define H_ 1024
#define PLANE (1 << 20)
#define TCOLS 64
#define TROWS 32
#define ROWS 8         // slow-path rows per ty slice (unchanged mapping)
#define KR 2           // output rows per thread (fast path)
#define LSTRIDE 76     // staged cols: x0-4 .. x0+71 (19 float4 groups)
#define GPR 19
#define NTILES 4       // tiles (y-bands) per persistent block
#define BUFSZ 9216     // floats: ITERS*256*4 worst case (IP=2: 2304 grp)

#define BX_ROWS 128    // rows per x-border block
#define BX_SLOTS 134   // BX_ROWS + 6 staged rows
#define BX_CH 1072     // BX_SLOTS * 8 floats per channel
#define BX_NG 804      // 3 * BX_SLOTS * 2 float4 groups

__device__ __forceinline__ float lerp1(float a, float b, float f) {
    return fmaf(f, b - a, a);
}

// async 16B global->LDS copy (gfx950). Dest must be linear in lane order.
__device__ __forceinline__ void async_copy16(const float* g, float* s) {
    __builtin_amdgcn_global_load_lds(
        (const __attribute__((address_space(1))) unsigned int*)g,
        (__attribute__((address_space(3))) unsigned int*)s,
        16, 0, 0);
}

// Exact per-pixel reference path (any sigma, any border) — verified R1-R15.
__device__ void slow_pixel(const float* __restrict__ Xb, float* __restrict__ Ob,
                           float sg, int xi, int y)
{
    float imf = floorf(-sg), ipf = floorf(sg);
    float fm  = -sg - imf;
    float fp  =  sg - ipf;
    int   im  = (int)imf, ip = (int)ipf;

    int cm0 = min(max(xi + im, 0), W_ - 1), cm1 = min(cm0 + 1, W_ - 1);
    int cp0 = min(max(xi + ip, 0), W_ - 1), cp1 = min(cp0 + 1, W_ - 1);
    int rm0 = min(max(y + im, 0), H_ - 1),  rm1 = min(rm0 + 1, H_ - 1);
    int rp0 = min(max(y + ip, 0), H_ - 1),  rp1 = min(rp0 + 1, H_ - 1);

    int o_rm0 = rm0 << 10, o_rm1 = rm1 << 10;
    int o_rp0 = rp0 << 10, o_rp1 = rp1 << 10;
    int o_r0  = y   << 10;

    float oxx = 0.f, oyy = 0.f, oxy = 0.f;

    #pragma unroll
    for (int c = 0; c < 3; ++c) {
        const float* base = Xb + ((size_t)c << 20);

        float hm_m0 = lerp1(base[o_rm0 + cm0], base[o_rm0 + cm1], fm);
        float hm_m1 = lerp1(base[o_rm1 + cm0], base[o_rm1 + cm1], fm);
        float hm_0  = lerp1(base[o_r0  + cm0], base[o_r0  + cm1], fm);
        float hm_p0 = lerp1(base[o_rp0 + cm0], base[o_rp0 + cm1], fm);
        float hm_p1 = lerp1(base[o_rp1 + cm0], base[o_rp1 + cm1], fm);
        float hp_m0 = lerp1(base[o_rm0 + cp0], base[o_rm0 + cp1], fp);
        float hp_m1 = lerp1(base[o_rm1 + cp0], base[o_rm1 + cp1], fp);
        float hp_0  = lerp1(base[o_r0  + cp0], base[o_r0  + cp1], fp);
        float hp_p0 = lerp1(base[o_rp0 + cp0], base[o_rp0 + cp1], fp);
        float hp_p1 = lerp1(base[o_rp1 + cp0], base[o_rp1 + cp1], fp);
        float h0_m0 = base[o_rm0 + xi], h0_m1 = base[o_rm1 + xi];
        float h0_p0 = base[o_rp0 + xi], h0_p1 = base[o_rp1 + xi];

        float t0 = lerp1(hm_m0, hm_m1, fm);
        float t1 = hm_0;
        float t2 = lerp1(hm_p0, hm_p1, fp);
        float t3 = lerp1(h0_m0, h0_m1, fm);
        float t4 = lerp1(h0_p0, h0_p1, fp);
        float t5 = lerp1(hp_m0, hp_m1, fm);
        float t6 = hp_0;
        float t7 = lerp1(hp_p0, hp_p1, fp);

        float su = 0.25f * (t5 + t7 - t0 - t2) + 0.5f * (t6 - t1);
        float sv = 0.25f * (t2 + t7 - t0 - t5) + 0.5f * (t4 - t3);

        float l2 = (c == 0) ? 10000.f : 1.f;
        oxx = fmaf(l2 * su, su, oxx);
        oyy = fmaf(l2 * sv, sv, oyy);
        oxy = fmaf(l2 * su, sv, oxy);
    }

    int pix = (y << 10) | xi;
    Ob[pix]             = oxx;
    Ob[PLANE + pix]     = oyy;
    Ob[2 * PLANE + pix] = oxy;
}

// x-border tile: stage 8 cols x 134 clamped rows x 3 ch into LDS, then
// compute the 3 border columns exactly (R15-verified).
template<int IP>
__device__ void border_x_tile(const float* __restrict__ Xb, float* __restrict__ Ob,
                              float fp, float fm, int side, int y0b,
                              int tid, float* smem)
{
    const int cb = side ? (W_ - 8) : 0;
    constexpr int im = -IP - 1, ip = IP;

    #pragma unroll
    for (int it = 0; it < 3; ++it) {
        int g   = it * 256 + tid;
        int ch  = g / 268;
        int rem = g - ch * 268;
        int slot = rem >> 1, grp = rem & 1;
        int rr  = min(max(y0b - 3 + slot, 0), H_ - 1);
        async_copy16(Xb + ((size_t)ch << 20) + (rr << 10) + cb + grp * 4,
                     smem + g * 4);
    }
    {
        int g = 768 + tid;
        if (g < BX_NG) {
            int ch  = g / 268;
            int rem = g - ch * 268;
            int slot = rem >> 1, grp = rem & 1;
            int rr  = min(max(y0b - 3 + slot, 0), H_ - 1);
            async_copy16(Xb + ((size_t)ch << 20) + (rr << 10) + cb + grp * 4,
                         smem + g * 4);
        }
    }
    __syncthreads();

    #pragma unroll
    for (int it = 0; it < 2; ++it) {
        int p = it * 256 + tid;
        if (p < 3 * BX_ROWS) {
            int r   = p / 3;
            int cc_ = p - r * 3;
            int y   = y0b + r;
            int xi  = cb + (side ? 5 + cc_ : cc_);

            int cm0 = min(max(xi + im, 0), W_ - 1), cm1 = min(cm0 + 1, W_ - 1);
            int cp0 = min(max(xi + ip, 0), W_ - 1), cp1 = min(cp0 + 1, W_ - 1);
            int rm0 = min(max(y + im, 0), H_ - 1),  rm1 = min(rm0 + 1, H_ - 1);
            int rp0 = min(max(y + ip, 0), H_ - 1),  rp1 = min(rp0 + 1, H_ - 1);

            int s_m0 = (rm0 - y0b + 3) << 3, s_m1 = (rm1 - y0b + 3) << 3;
            int s_p0 = (rp0 - y0b + 3) << 3, s_p1 = (rp1 - y0b + 3) << 3;
            int s_0  = (y   - y0b + 3) << 3;
            int lm0 = cm0 - cb, lm1 = cm1 - cb;
            int lp0 = cp0 - cb, lp1 = cp1 - cb;
            int lxi = xi - cb;

            float oxx = 0.f, oyy = 0.f, oxy = 0.f;
            #pragma unroll
            for (int c = 0; c < 3; ++c) {
                const float* base = smem + c * BX_CH;

                float hm_m0 = lerp1(base[s_m0 + lm0], base[s_m0 + lm1], fm);
                float hm_m1 = lerp1(base[s_m1 + lm0], base[s_m1 + lm1], fm);
                float hm_0  = lerp1(base[s_0  + lm0], base[s_0  + lm1], fm);
                float hm_p0 = lerp1(base[s_p0 + lm0], base[s_p0 + lm1], fm);
                float hm_p1 = lerp1(base[s_p1 + lm0], base[s_p1 + lm1], fm);
                float hp_m0 = lerp1(base[s_m0 + lp0], base[s_m0 + lp1], fp);
                float hp_m1 = lerp1(base[s_m1 + lp0], base[s_m1 + lp1], fp);
                float hp_0  = lerp1(base[s_0  + lp0], base[s_0  + lp1], fp);
                float hp_p0 = lerp1(base[s_p0 + lp0], base[s_p0 + lp1], fp);
                float hp_p1 = lerp1(base[s_p1 + lp0], base[s_p1 + lp1], fp);
                float h0_m0 = base[s_m0 + lxi], h0_m1 = base[s_m1 + lxi];
                float h0_p0 = base[s_p0 + lxi], h0_p1 = base[s_p1 + lxi];

                float t0 = lerp1(hm_m0, hm_m1, fm);
                float t1 = hm_0;
                float t2 = lerp1(hm_p0, hm_p1, fp);
                float t3 = lerp1(h0_m0, h0_m1, fm);
                float t4 = lerp1(h0_p0, h0_p1, fp);
                float t5 = lerp1(hp_m0, hp_m1, fm);
                float t6 = hp_0;
                float t7 = lerp1(hp_p0, hp_p1, fp);

                float su = 0.25f * (t5 + t7 - t0 - t2) + 0.5f * (t6 - t1);
                float sv = 0.25f * (t2 + t7 - t0 - t5) + 0.5f * (t4 - t3);

                float l2 = (c == 0) ? 10000.f : 1.f;
                oxx = fmaf(l2 * su, su, oxx);
                oyy = fmaf(l2 * sv, sv, oyy);
                oxy = fmaf(l2 * su, sv, oxy);
            }

            int pix = (y << 10) | xi;
            Ob[pix]             = oxx;
            Ob[PLANE + pix]     = oyy;
            Ob[2 * PLANE + pix] = oxy;
        }
    }
}

template<int N>
__device__ __forceinline__ void accf(float (&arr)[N], int k, float w, float v) {
    if (k >= 0 && k < N) arr[k] = fmaf(w, v, arr[k]);   // k const after unroll
}

// Persistent fast block: cols x0..x0+63, bands band0..band0+3. Threads:
// xg = tx&15 owns cols x0+4xg..+3; yg = ty*4 + (tx>>4) owns rows
// y0+2yg..+1. Per (window row, ch): 3 aligned ds_read_b128 give 12
// dwords covering all taps of the 4 cols; separable d/e accumulate.
// Stores: 24 scalar dwords/thread (preserves vmcnt(9) bookkeeping).
template<int IP>
__device__ void fast_tiles(const float* __restrict__ Xb, float* __restrict__ Ob,
                           float fp, float fm, int x0, int band0,
                           int tx, int ty, int tid, float* smem)
{
    constexpr int LROWS = TROWS + 2 * IP + 2;   // staged rows per channel
    constexpr int RW    = KR + 2 * IP + 2;      // window rows per thread
    constexpr int NG    = 3 * LROWS * GPR;      // float4 groups per tile
    constexpr int ITERS = (NG + 255) / 256;     // copies per thread (uniform)

    const int xg = tx & 15;
    const int yg = ty * 4 + (tx >> 4);
    const int X  = xg << 2;                     // block-local first col
    const int gx = x0 + X;
    const float fp4 = 0.25f * fp, fm4 = 0.25f * fm;

    // Exec-uniform staging (R13-proven): clamped tail junk lands at
    // linear positions NG..ITERS*256-1 inside BUFSZ.
    auto stage = [&](float* buf, int y0) {
        #pragma unroll
        for (int it = 0; it < ITERS; ++it) {
            int g    = min(it * 256 + tid, NG - 1);
            int row  = g / GPR;
            int grp  = g - row * GPR;
            int c    = row / LROWS;
            int lrow = row - c * LROWS;
            int gr   = min(max(y0 - IP - 1 + lrow, 0), H_ - 1);
            int gc   = min(max(x0 - 4 + grp * 4, 0), W_ - 4);
            async_copy16(Xb + ((size_t)c << 20) + (gr << 10) + gc,
                         buf + g * 4);
        }
    };

    stage(smem,         (band0 + 0) * TROWS);
    stage(smem + BUFSZ, (band0 + 1) * TROWS);

    #pragma unroll
    for (int t = 0; t < NTILES; ++t) {
        float* buf = smem + (t & 1) * BUFSZ;
        int y0 = (band0 + t) * TROWS;

        if constexpr (ITERS >= 9) asm volatile("s_waitcnt vmcnt(9)" ::: "memory");
        else                      asm volatile("s_waitcnt vmcnt(8)" ::: "memory");
        __builtin_amdgcn_s_barrier();

        float oxx[4][KR], oyy[4][KR], oxy[4][KR];
        #pragma unroll
        for (int c4 = 0; c4 < 4; ++c4)
            #pragma unroll
            for (int k = 0; k < KR; ++k)
                { oxx[c4][k] = 0.f; oyy[c4][k] = 0.f; oxy[c4][k] = 0.f; }

        #pragma unroll
        for (int c = 0; c < 3; ++c) {
            const float* sp = buf + (c * LROWS + yg * KR) * LSTRIDE + X;

            float su[4][KR], sv[4][KR];
            #pragma unroll
            for (int c4 = 0; c4 < 4; ++c4)
                #pragma unroll
                for (int k = 0; k < KR; ++k) { su[c4][k] = 0.f; sv[c4][k] = 0.f; }

            #pragma unroll
            for (int w = 0; w < RW; ++w) {
                const float4 q0 = *reinterpret_cast<const float4*>(sp + w * LSTRIDE);
                const float4 q1 = *reinterpret_cast<const float4*>(sp + w * LSTRIDE + 4);
                const float4 q2 = *reinterpret_cast<const float4*>(sp + w * LSTRIDE + 8);
                float v[12] = {q0.x, q0.y, q0.z, q0.w,
                               q1.x, q1.y, q1.z, q1.w,
                               q2.x, q2.y, q2.z, q2.w};
                #pragma unroll
                for (int c4 = 0; c4 < 4; ++c4) {
                    float a0 = v[c4 + 3 - IP], a1 = v[c4 + 4 - IP];
                    float cc = v[c4 + 4];
                    float b0 = v[c4 + 4 + IP], b1 = v[c4 + 5 + IP];
                    float hm = lerp1(a0, a1, fm);
                    float hp = lerp1(b0, b1, fp);
                    float d  = hp - hm;               // = q
                    float e  = fmaf(0.5f, cc, 0.25f * (hm + hp));   // = Bv
                    accf(su[c4], w,              fp4,  d);
                    accf(su[c4], w - 1,          fm4,  d);
                    accf(su[c4], w - IP - 1,     0.5f, d);
                    accf(su[c4], w - 2*IP - 1,   fm4,  d);
                    accf(su[c4], w - 2*IP - 2,   fp4,  d);
                    accf(sv[c4], w,             -fp,   e);
                    accf(sv[c4], w - 1,         -fm,   e);
                    accf(sv[c4], w - 2*IP - 1,   fm,   e);
                    accf(sv[c4], w - 2*IP - 2,   fp,   e);
                }
            }

            float l2 = (c == 0) ? 10000.f : 1.f;
            #pragma unroll
            for (int c4 = 0; c4 < 4; ++c4)
                #pragma unroll
                for (int k = 0; k < KR; ++k) {
                    oxx[c4][k] = fmaf(l2 * su[c4][k], su[c4][k], oxx[c4][k]);
                    oyy[c4][k] = fmaf(l2 * sv[c4][k], sv[c4][k], oyy[c4][k]);
                    oxy[c4][k] = fmaf(l2 * su[c4][k], sv[c4][k], oxy[c4][k]);
                }
        }

        // 24 scalar dword stores/thread (vmcnt bookkeeping as R13-15).
        bool okc[4];
        #pragma unroll
        for (int c4 = 0; c4 < 4; ++c4)
            okc[c4] = (gx + c4 > IP) && (gx + c4 < W_ - 1 - IP);
        #pragma unroll
        for (int k = 0; k < KR; ++k) {
            int y = y0 + yg * KR + k;
            if (y > IP) {
                int pix = (y << 10) + gx;
                #pragma unroll
                for (int c4 = 0; c4 < 4; ++c4) {
                    if (okc[c4]) {
                        Ob[pix + c4]             = oxx[c4][k];
                        Ob[PLANE + pix + c4]     = oyy[c4][k];
                        Ob[2 * PLANE + pix + c4] = oxy[c4][k];
                    }
                }
            }
        }

        asm volatile("s_waitcnt lgkmcnt(0)" ::: "memory");
        __builtin_amdgcn_s_barrier();
        if (t + 2 < NTILES)
            stage(buf, (band0 + t + 2) * TROWS);
    }
}

// block (64,4). grid = (16, 10, 4):
//   y==0: 16 x-border tiles; y==1: 12 y-border-row blocks; y>=2: fast.
__global__ __launch_bounds__(256, 1) void st_kernel(
    const float* __restrict__ X, const float* __restrict__ S,
    float* __restrict__ O)
{
    int b  = blockIdx.z;
    const float* Xb = X + (size_t)b * 3 * PLANE;
    float*       Ob = O + (size_t)b * 3 * PLANE;
    float sg = S[b];

    int tx = threadIdx.x, ty = threadIdx.y;
    int tid = ty * 64 + tx;

    int ipv = (int)floorf(sg);
    int imv = (int)floorf(-sg);
    bool sig_ok = (imv == -ipv - 1) && ipv >= 0 && ipv <= 2;  // block-uniform
    float fp = sg - (float)ipv;
    float fm = 1.0f - fp;

    __shared__ __align__(16) float smem[2 * BUFSZ];

    if (blockIdx.y == 0) {
        int side = blockIdx.x & 1;
        int y0b  = (blockIdx.x >> 1) * BX_ROWS;
        if (sig_ok) {
            switch (ipv) {
                case 0:  border_x_tile<0>(Xb, Ob, fp, fm, side, y0b, tid, smem); break;
                case 1:  border_x_tile<1>(Xb, Ob, fp, fm, side, y0b, tid, smem); break;
                default: border_x_tile<2>(Xb, Ob, fp, fm, side, y0b, tid, smem); break;
            }
        } else {
            for (int it = 0; it < 2; ++it) {
                int p = it * 256 + tid;
                if (p < 3 * BX_ROWS) {
                    int r = p / 3, cc = p - r * 3;
                    int xi = side ? 1021 + cc : cc;
                    slow_pixel(Xb, Ob, sg, xi, y0b + r);
                }
            }
        }
        return;
    }

    if (blockIdx.y == 1) {
        int p = blockIdx.x * 256 + tid;
        if (p < 3072) slow_pixel(Xb, Ob, sg, p & 1023, p >> 10);
        return;
    }

    int x0    = blockIdx.x * TCOLS;
    int band0 = (blockIdx.y - 2) * NTILES;

    if (sig_ok) {
        switch (ipv) {
            case 0:  fast_tiles<0>(Xb, Ob, fp, fm, x0, band0, tx, ty, tid, smem); break;
            case 1:  fast_tiles<1>(Xb, Ob, fp, fm, x0, band0, tx, ty, tid, smem); break;
            default: fast_tiles<2>(Xb, Ob, fp, fm, x0, band0, tx, ty, tid, smem); break;
        }
    } else {
        for (int t = 0; t < NTILES; ++t)
            for (int k = 0; k < ROWS; ++k)
                slow_pixel(Xb, Ob, sg, x0 + tx,
                           (band0 + t) * TROWS + ty * ROWS + k);
    }
}

extern "C" void kernel_launch(void* const* d_in, const int* in_sizes, int n_in,
                              void* d_out, int out_size, void* d_ws, size_t ws_size,
                              hipStream_t stream) {
    const float* x     = (const float*)d_in[0];
    const float* sigma = (const float*)d_in[1];
    float* out = (float*)d_out;

    dim3 grid(W_ / TCOLS, H_ / TROWS / NTILES + 2, 4), block(64, 4);
    hipLaunchKernelGGL(st_kernel, grid, block, 0, stream, x, sigma, out);
}